// Round 12
// baseline (464.737 us; speedup 1.0000x reference)
//
#include <hip/hip_runtime.h>

#define NN 50000
#define HD 128
#define NL 4
#define BN_EPS 1e-5f
#define NTILES 3125
#define MAXDEG 64
// XOR-swizzle for unpadded w4 (16B entries): spreads the m-stride-16 read
// pattern over 4 bank groups (16-way conflict -> ~4-way).
#define WSWZ(e) ((e) ^ (((e) >> 4) & 3))

typedef __attribute__((ext_vector_type(8))) short short8;
typedef __attribute__((ext_vector_type(4))) float f32x4;
typedef __attribute__((ext_vector_type(4))) uint uint4v;

__device__ inline ushort f2bf(float f){
  uint u = __float_as_uint(f);
  uint r = (u + 0x7fffu + ((u >> 16) & 1u)) >> 16;
  return (ushort)r;
}
__device__ inline float bflo(uint u){ return __uint_as_float(u << 16); }
__device__ inline float bfhi(uint u){ return __uint_as_float(u & 0xffff0000u); }
__device__ inline uint pk2(float lo, float hi){
  return (uint)f2bf(lo) | ((uint)f2bf(hi) << 16);
}

// ---------------- fused cast fp32 -> bf16 (+ workspace zero-fill) ----------------
__global__ __launch_bounds__(256) void cast_all(const float* __restrict__ x,
                                                const float* __restrict__ w1,
                                                const float* __restrict__ w2,
                                                const float* __restrict__ wf,
                                                ushort* __restrict__ xb,
                                                ushort* __restrict__ wb,
                                                uint* __restrict__ zptr){
  const int ZB4 = 16600;               // 265600 B of cnt+stats as uint4
  {
    int z = blockIdx.x * 256 + threadIdx.x;
    int zstride = gridDim.x * 256;
    uint4v zero = (uint4v)0u;
    for (; z < ZB4; z += zstride) ((uint4v*)zptr)[z] = zero;
  }
  const int NX = NN * HD / 4;          // 1,600,000 uint4-groups of x
  const int NT = NX + 36864;           // + weights
  int i = blockIdx.x * 256 + threadIdx.x;
  int stride = gridDim.x * 256;
  for (; i < NT; i += stride){
    const float* src; ushort* dst;
    if (i < NX){ src = x + i * 4; dst = xb + i * 4; }
    else {
      int k = i - NX;
      dst = wb + k * 4;
      if (k < 16384)      src = w1 + k * 4;
      else if (k < 32768) src = w2 + (k - 16384) * 4;
      else                src = wf + (k - 32768) * 4;
    }
    float4 v = *(const float4*)src;
    ushort4 r;
    r.x = f2bf(v.x); r.y = f2bf(v.y); r.z = f2bf(v.z); r.w = f2bf(v.w);
    *(ushort4*)dst = r;
  }
}

// ---------------- bucketed CSR build (no scan) ----------------
__global__ void fill1_kernel(const int* __restrict__ dst, int* __restrict__ cnt,
                             int* __restrict__ pos, int E){
  int e = (blockIdx.x * 256 + threadIdx.x) * 4;
  if (e + 4 <= E){
    int4 d = *(const int4*)(dst + e);
    int4 p;
    p.x = atomicAdd(&cnt[d.x], 1);
    p.y = atomicAdd(&cnt[d.y], 1);
    p.z = atomicAdd(&cnt[d.z], 1);
    p.w = atomicAdd(&cnt[d.w], 1);
    *(int4*)(pos + e) = p;
  } else {
    for (; e < E; ++e) pos[e] = atomicAdd(&cnt[dst[e]], 1);
  }
}

__global__ void fill2_kernel(const int* __restrict__ src, const int* __restrict__ dst,
                             const int* __restrict__ pos, int* __restrict__ slots, int E){
  int e = (blockIdx.x * 256 + threadIdx.x) * 4;
  if (e + 4 <= E){
    int4 d = *(const int4*)(dst + e);
    int4 p = *(const int4*)(pos + e);
    int4 s = *(const int4*)(src + e);
    slots[d.x * MAXDEG + p.x] = s.x;
    slots[d.y * MAXDEG + p.y] = s.y;
    slots[d.z * MAXDEG + p.z] = s.z;
    slots[d.w * MAXDEG + p.w] = s.w;
  } else {
    for (; e < E; ++e) slots[dst[e] * MAXDEG + pos[e]] = src[e];
  }
}

// ---------------- BN param computation (device helper, threads<128) ----------------
__device__ inline void bn_params8(const float* __restrict__ st, const float* __restrict__ gA,
                                  const float* __restrict__ gB, const float* __restrict__ bB,
                                  int mode, float* sS, float* sT){
  int c = threadIdx.x;
  if (c < 128){
    float s0 = 0.f, s1 = 0.f;
#pragma unroll
    for (int k = 0; k < 8; ++k){
      s0 += st[k * 256 + c];
      s1 += st[k * 256 + 128 + c];
    }
    const float invN = 1.f / (float)NN;
    float mu = s0 * invN;
    float var = fmaxf(s1 * invN - mu * mu, 0.f);
    float S, T;
    if (mode == 0){
      S = gA[c] * rsqrtf(var + BN_EPS);
      T = gB[c] - mu * S;
    } else {
      float inv2 = rsqrtf(var + BN_EPS);
      float tt = gA[c] * inv2;
      float inv3 = rsqrtf(tt * tt * var + BN_EPS);
      S = tt * inv3 * gB[c];
      T = bB[c] - mu * S;
    }
    sS[c] = S; sT[c] = T;
  }
}

// ---------------- fused aggregation + fc1 GEMM (3-blocks/CU geometry) ----------------
// 4 tiles/block, 2 waves/tile. Gather: each wave owns 8 rows (2 quads of 4 nodes,
// 16 lanes/row) -> halved serial chain vs R5. LDS 52.2KB -> 3 blocks/CU = 24
// gather-waves/CU (+50% MLP vs R5's 16). w4 is unpadded+XOR-swizzled to fit.
// Phase 2: each wave computes its tile's col-half (acc[4]).
template<bool AFF>
__global__ __launch_bounds__(512, 6) void aggemm_t(const ushort* __restrict__ xin,
                                                   const int* __restrict__ deg,
                                                   const int* __restrict__ slots,
                                                   const ushort* __restrict__ W,
                                                   const float* __restrict__ bias,
                                                   ushort* __restrict__ Yb,
                                                   float* __restrict__ statsOut,
                                                   const float* __restrict__ statsIn,
                                                   const float* __restrict__ g2,
                                                   const float* __restrict__ g3,
                                                   const float* __restrict__ b3){
  __shared__ uint4v w4[2048];         // 32KB, unpadded, XOR-swizzled
  __shared__ uint4v a4[4][16 * 17];   // 4 x 4.35KB padded A-tiles
  __shared__ float ssum[128];
  __shared__ float ssq[128];
  __shared__ float sS[128];
  __shared__ float sT[128];

  const uint4v* Wg = (const uint4v*)W;
  for (int c = threadIdx.x; c < 2048; c += 512){
    w4[WSWZ(c)] = Wg[c];
  }
  if (AFF) bn_params8(statsIn, g2, g3, b3, 1, sS, sT);
  if (threadIdx.x < 128){ ssum[threadIdx.x] = 0.f; ssq[threadIdx.x] = 0.f; }
  __syncthreads();

  int wave = threadIdx.x >> 6;
  int lane = threadIdx.x & 63;
  int tl   = wave >> 1;          // local tile 0..3
  int hf   = wave & 1;           // row-half of the tile (gather) / col-half (mfma)
  int grp  = lane >> 4;          // which of the 4 concurrent node slots
  int col  = lane & 15;          // 16B chunk within the 256B row
  int tile = blockIdx.x * 4 + tl;
  bool tv = tile < NTILES;

  float S[8], T[8];
  if (AFF){
#pragma unroll
    for (int k = 0; k < 8; ++k){ S[k] = sS[col * 8 + k]; T[k] = sT[col * 8 + k]; }
  }

  const uint4v* x4 = (const uint4v*)xin;

#define INIT8(v)                                                                \
  if (AFF){                                                                     \
    a[0]=fmaxf(bflo((v).x)*S[0]+T[0],0.f); a[1]=fmaxf(bfhi((v).x)*S[1]+T[1],0.f); \
    a[2]=fmaxf(bflo((v).y)*S[2]+T[2],0.f); a[3]=fmaxf(bfhi((v).y)*S[3]+T[3],0.f); \
    a[4]=fmaxf(bflo((v).z)*S[4]+T[4],0.f); a[5]=fmaxf(bfhi((v).z)*S[5]+T[5],0.f); \
    a[6]=fmaxf(bflo((v).w)*S[6]+T[6],0.f); a[7]=fmaxf(bfhi((v).w)*S[7]+T[7],0.f); \
  } else {                                                                      \
    a[0]=bflo((v).x); a[1]=bfhi((v).x); a[2]=bflo((v).y); a[3]=bfhi((v).y);     \
    a[4]=bflo((v).z); a[5]=bfhi((v).z); a[6]=bflo((v).w); a[7]=bfhi((v).w);     \
  }

#define ACC8(v)                                                                 \
  if (AFF){                                                                     \
    a[0]+=fmaxf(bflo((v).x)*S[0]+T[0],0.f); a[1]+=fmaxf(bfhi((v).x)*S[1]+T[1],0.f); \
    a[2]+=fmaxf(bflo((v).y)*S[2]+T[2],0.f); a[3]+=fmaxf(bfhi((v).y)*S[3]+T[3],0.f); \
    a[4]+=fmaxf(bflo((v).z)*S[4]+T[4],0.f); a[5]+=fmaxf(bfhi((v).z)*S[5]+T[5],0.f); \
    a[6]+=fmaxf(bflo((v).w)*S[6]+T[6],0.f); a[7]+=fmaxf(bfhi((v).w)*S[7]+T[7],0.f); \
  } else {                                                                      \
    a[0]+=bflo((v).x); a[1]+=bfhi((v).x); a[2]+=bflo((v).y); a[3]+=bfhi((v).y); \
    a[4]+=bflo((v).z); a[5]+=bfhi((v).z); a[6]+=bflo((v).w); a[7]+=bfhi((v).w); \
  }

  if (tv){
    for (int it = 0; it < 2; ++it){
      int lrow = hf * 8 + it * 4 + grp;
      int node = tile * 16 + lrow;
      int e = deg[node];
      const int* sl = slots + node * MAXDEG;
      float a[8];
      {
        uint4v v = x4[node * 16 + col];
        INIT8(v);
      }
      int j = 0;
      for (; j + 8 <= e; j += 8){
        int i0 = sl[j+0], i1 = sl[j+1], i2 = sl[j+2], i3 = sl[j+3];
        int i4 = sl[j+4], i5 = sl[j+5], i6 = sl[j+6], i7 = sl[j+7];
        uint4v v0 = x4[i0 * 16 + col];
        uint4v v1 = x4[i1 * 16 + col];
        uint4v v2 = x4[i2 * 16 + col];
        uint4v v3 = x4[i3 * 16 + col];
        uint4v v4 = x4[i4 * 16 + col];
        uint4v v5 = x4[i5 * 16 + col];
        uint4v v6 = x4[i6 * 16 + col];
        uint4v v7 = x4[i7 * 16 + col];
        ACC8(v0); ACC8(v1); ACC8(v2); ACC8(v3);
        ACC8(v4); ACC8(v5); ACC8(v6); ACC8(v7);
      }
      for (; j + 4 <= e; j += 4){
        int i0 = sl[j+0], i1 = sl[j+1], i2 = sl[j+2], i3 = sl[j+3];
        uint4v v0 = x4[i0 * 16 + col];
        uint4v v1 = x4[i1 * 16 + col];
        uint4v v2 = x4[i2 * 16 + col];
        uint4v v3 = x4[i3 * 16 + col];
        ACC8(v0); ACC8(v1); ACC8(v2); ACC8(v3);
      }
      for (; j < e; ++j){
        uint4v v = x4[sl[j] * 16 + col];
        ACC8(v);
      }
      uint4v o;
      o.x = pk2(a[0], a[1]); o.y = pk2(a[2], a[3]);
      o.z = pk2(a[4], a[5]); o.w = pk2(a[6], a[7]);
      a4[tl][lrow * 17 + col] = o;
    }
  }
#undef INIT8
#undef ACC8
  __syncthreads();

  // ---- phase 2: MFMA; this wave computes its tile's col-half (4 blocks) ----
  int m = lane & 15, q = lane >> 4;
  f32x4 acc[4];
#pragma unroll
  for (int i = 0; i < 4; ++i) acc[i] = (f32x4)0.f;

#pragma unroll
  for (int kt = 0; kt < 4; ++kt){
    uint4v t = a4[tl][m * 17 + kt * 4 + q];
    short8 af = *(short8*)&t;
#pragma unroll
    for (int t4 = 0; t4 < 4; ++t4){
      int to = hf * 4 + t4;
      int e = (to * 16 + m) * 16 + kt * 4 + q;
      uint4v bw = w4[WSWZ(e)];
      acc[t4] = __builtin_amdgcn_mfma_f32_16x16x32_bf16(af, *(short8*)&bw, acc[t4], 0, 0, 0);
    }
  }

#pragma unroll
  for (int t4 = 0; t4 < 4; ++t4){
    int colo = (hf * 4 + t4) * 16 + m;
    float bc = bias[colo];
    float ls = 0.f, lq = 0.f;
    if (tv){
#pragma unroll
      for (int r = 0; r < 4; ++r){
        float v = acc[t4][r] + bc;
        int row = tile * 16 + q * 4 + r;
        __builtin_nontemporal_store(__builtin_bit_cast(ushort, f2bf(v)), Yb + row * 128 + colo);
        ls += v; lq += v * v;
      }
    }
    ls += __shfl_xor(ls, 16); lq += __shfl_xor(lq, 16);
    ls += __shfl_xor(ls, 32); lq += __shfl_xor(lq, 32);
    if (tv && q == 0){ atomicAdd(&ssum[colo], ls); atomicAdd(&ssq[colo], lq); }
  }
  __syncthreads();
  if (threadIdx.x < 128){
    int sb = (blockIdx.x & 7) * 256;
    atomicAdd(&statsOut[sb + threadIdx.x], ssum[threadIdx.x]);
    atomicAdd(&statsOut[sb + 128 + threadIdx.x], ssq[threadIdx.x]);
  }
}

// ---------------- unified GEMM: Y = [relu(affine(A))] @ W^T + bias ----------------
// 512 threads, 8 waves, 1 tile (16 rows) per wave; grid 391. (R5-proven, untouched)
__global__ __launch_bounds__(512) void gemm_kernel(const ushort* __restrict__ A,
                                                   const ushort* __restrict__ W,
                                                   const float* __restrict__ bias,
                                                   ushort* __restrict__ Yb,
                                                   float* __restrict__ Yf,
                                                   float* __restrict__ statsOut,
                                                   const float* __restrict__ statsIn,
                                                   const float* __restrict__ gA,
                                                   const float* __restrict__ gB,
                                                   const float* __restrict__ bB,
                                                   int mode){
  __shared__ uint4v w4[128 * 17];
  __shared__ float ssum[128];
  __shared__ float ssq[128];
  __shared__ float sS[128];
  __shared__ float sT[128];
  const uint4v* Wg = (const uint4v*)W;
  for (int c = threadIdx.x; c < 2048; c += 512){
    w4[(c >> 4) * 17 + (c & 15)] = Wg[c];
  }
  if (statsIn) bn_params8(statsIn, gA, gB, bB, mode, sS, sT);
  if (threadIdx.x < 128){ ssum[threadIdx.x] = 0.f; ssq[threadIdx.x] = 0.f; }
  __syncthreads();

  int wave = threadIdx.x >> 6;
  int lane = threadIdx.x & 63;
  int m = lane & 15, q = lane >> 4;
  int tile = blockIdx.x * 8 + wave;
  bool tv = tile < NTILES;
  const uint4v* A4 = (const uint4v*)A;

  f32x4 acc[8];
#pragma unroll
  for (int i = 0; i < 8; ++i) acc[i] = (f32x4)0.f;

#pragma unroll
  for (int kt = 0; kt < 4; ++kt){
    short8 af = (short8)0;
    if (tv){
      uint4v t = __builtin_nontemporal_load(A4 + (tile * 16 + m) * 16 + kt * 4 + q);
      if (statsIn){
        int kc = kt * 32 + q * 8;
        uint4v pk;
        pk.x = pk2(fmaxf(bflo(t.x)*sS[kc+0]+sT[kc+0],0.f),
                   fmaxf(bfhi(t.x)*sS[kc+1]+sT[kc+1],0.f));
        pk.y = pk2(fmaxf(bflo(t.y)*sS[kc+2]+sT[kc+2],0.f),
                   fmaxf(bfhi(t.y)*sS[kc+3]+sT[kc+3],0.f));
        pk.z = pk2(fmaxf(bflo(t.z)*sS[kc+4]+sT[kc+4],0.f),
                   fmaxf(bfhi(t.z)*sS[kc+5]+sT[kc+5],0.f));
        pk.w = pk2(fmaxf(bflo(t.w)*sS[kc+6]+sT[kc+6],0.f),
                   fmaxf(bfhi(t.w)*sS[kc+7]+sT[kc+7],0.f));
        t = pk;
      }
      af = *(short8*)&t;
    }
#pragma unroll
    for (int to = 0; to < 8; ++to){
      uint4v bw = w4[(to * 16 + m) * 17 + kt * 4 + q];
      acc[to] = __builtin_amdgcn_mfma_f32_16x16x32_bf16(af, *(short8*)&bw, acc[to], 0, 0, 0);
    }
  }

  bool dost = (statsOut != nullptr);
#pragma unroll
  for (int to = 0; to < 8; ++to){
    int col = to * 16 + m;
    float bc = bias[col];
    float ls = 0.f, lq = 0.f;
    if (tv){
#pragma unroll
      for (int r = 0; r < 4; ++r){
        float v = acc[to][r] + bc;
        int row = tile * 16 + q * 4 + r;
        if (Yb) __builtin_nontemporal_store(__builtin_bit_cast(ushort, f2bf(v)), Yb + row * 128 + col);
        else    __builtin_nontemporal_store(v, Yf + row * 128 + col);
        ls += v; lq += v * v;
      }
    }
    if (dost){
      ls += __shfl_xor(ls, 16); lq += __shfl_xor(lq, 16);
      ls += __shfl_xor(ls, 32); lq += __shfl_xor(lq, 32);
      if (tv && q == 0){ atomicAdd(&ssum[col], ls); atomicAdd(&ssq[col], lq); }
    }
  }
  if (dost){
    __syncthreads();
    if (threadIdx.x < 128){
      int sb = (blockIdx.x & 7) * 256;
      atomicAdd(&statsOut[sb + threadIdx.x], ssum[threadIdx.x]);
      atomicAdd(&statsOut[sb + 128 + threadIdx.x], ssq[threadIdx.x]);
    }
  }
}

extern "C" void kernel_launch(void* const* d_in, const int* in_sizes, int n_in,
                              void* d_out, int out_size, void* d_ws, size_t ws_size,
                              hipStream_t stream) {
  const float* x     = (const float*)d_in[0];
  const int*   ei    = (const int*)d_in[1];
  const float* fc1_w = (const float*)d_in[2];
  const float* fc1_b = (const float*)d_in[3];
  const float* bn1_g = (const float*)d_in[4];
  const float* bn1_b = (const float*)d_in[5];
  const float* fc2_w = (const float*)d_in[6];
  const float* fc2_b = (const float*)d_in[7];
  const float* bn2_g = (const float*)d_in[8];
  const float* bn3_g = (const float*)d_in[10];
  const float* bn3_b = (const float*)d_in[11];
  const float* fc_w  = (const float*)d_in[12];
  const float* fc_b  = (const float*)d_in[13];

  int E = in_sizes[1] / 2;
  const int* srcp = ei;
  const int* dstp = ei + E;

  char* ws = (char*)d_ws;
  int*    cnt    = (int*)(ws + 0);           // N ints (degree)
  float*  stats  = (float*)(ws + 200064);    // 8 slices x 8 sub x 256 floats = 64KB
  int*    pos    = (int*)(ws + 265600);      // E ints
  int*    slots  = (int*)(ws + 3465600);     // N*MAXDEG ints = 12.8 MB
  ushort* wb     = (ushort*)(ws + 16265600); // 147456 bf16
  ushort* xb     = (ushort*)(ws + 16560512); // N*128 bf16
  ushort* y1b    = (ushort*)(ws + 29360512); // N*128 bf16
  ushort* y2b    = (ushort*)(ws + 42160512); // N*128 bf16

  // cast_all also zeroes cnt+stats (contiguous 265600 B at ws start)
  cast_all<<<2048, 256, 0, stream>>>(x, fc1_w, fc2_w, fc_w, xb, wb, (uint*)ws);

  const int EB4 = (E / 4 + 255) / 256 + 1;
  fill1_kernel<<<EB4, 256, 0, stream>>>(dstp, cnt, pos, E);
  fill2_kernel<<<EB4, 256, 0, stream>>>(srcp, dstp, pos, slots, E);

  const int ga = (NTILES + 3) / 4;  // 782 blocks x 4 tiles (aggemm)
  const int gb = (NTILES + 7) / 8;  // 391 blocks x 8 waves (gemm)

  for (int i = 0; i < NL; ++i){
    // fused agg + fc1: gather (+bn23 affine for i>0) -> LDS tile -> MFMA -> y1b, stats1
    if (i == 0){
      aggemm_t<false><<<ga, 512, 0, stream>>>(xb, cnt, slots, wb + i * 16384,
                                              fc1_b + i * 128, y1b,
                                              stats + (i * 2) * 2048,
                                              nullptr, nullptr, nullptr, nullptr);
    } else {
      aggemm_t<true><<<ga, 512, 0, stream>>>(y2b, cnt, slots, wb + i * 16384,
                                             fc1_b + i * 128, y1b,
                                             stats + (i * 2) * 2048,
                                             stats + ((i - 1) * 2 + 1) * 2048,
                                             bn2_g + (i - 1) * 128,
                                             bn3_g + (i - 1) * 128,
                                             bn3_b + (i - 1) * 128);
    }
    // fc2: relu(bn1(y1b)) -> y2b (bf16), stats2; bn1 params inline from stats1
    gemm_kernel<<<gb, 512, 0, stream>>>(y1b, wb + 65536 + i * 16384, fc2_b + i * 128,
                                        y2b, nullptr, stats + (i * 2 + 1) * 2048,
                                        stats + (i * 2) * 2048, bn1_g + i * 128,
                                        bn1_b + i * 128, nullptr, 0);
  }

  // classifier: relu(bn3(bn2(y2b)))@fc_w^T + fc_b -> f32 out; bn23 params inline
  gemm_kernel<<<gb, 512, 0, stream>>>(y2b, wb + 131072, fc_b,
                                      nullptr, (float*)d_out, nullptr,
                                      stats + 7 * 2048, bn2_g + 384,
                                      bn3_g + 384, bn3_b + 384, 1);
}

// Round 13
// 424.046 us; speedup vs baseline: 1.0960x; 1.0960x over previous
//
#include <hip/hip_runtime.h>

#define NN 50000
#define HD 128
#define NL 4
#define BN_EPS 1e-5f
#define NTILES 3125
#define MAXDEG 64

typedef __attribute__((ext_vector_type(8))) short short8;
typedef __attribute__((ext_vector_type(4))) float f32x4;
typedef __attribute__((ext_vector_type(4))) uint uint4v;

__device__ inline ushort f2bf(float f){
  uint u = __float_as_uint(f);
  uint r = (u + 0x7fffu + ((u >> 16) & 1u)) >> 16;
  return (ushort)r;
}
__device__ inline float bflo(uint u){ return __uint_as_float(u << 16); }
__device__ inline float bfhi(uint u){ return __uint_as_float(u & 0xffff0000u); }
__device__ inline uint pk2(float lo, float hi){
  return (uint)f2bf(lo) | ((uint)f2bf(hi) << 16);
}

// ---------------- fused cast fp32 -> bf16 : x then all weights ----------------
__global__ __launch_bounds__(256) void cast_all(const float* __restrict__ x,
                                                const float* __restrict__ w1,
                                                const float* __restrict__ w2,
                                                const float* __restrict__ wf,
                                                ushort* __restrict__ xb,
                                                ushort* __restrict__ wb){
  const int NX = NN * HD / 4;          // 1,600,000 uint4-groups of x
  const int NT = NX + 36864;           // + weights
  int i = blockIdx.x * 256 + threadIdx.x;
  int stride = gridDim.x * 256;
  for (; i < NT; i += stride){
    const float* src; ushort* dst;
    if (i < NX){ src = x + i * 4; dst = xb + i * 4; }
    else {
      int k = i - NX;
      dst = wb + k * 4;
      if (k < 16384)      src = w1 + k * 4;
      else if (k < 32768) src = w2 + (k - 16384) * 4;
      else                src = wf + (k - 32768) * 4;
    }
    float4 v = *(const float4*)src;
    ushort4 r;
    r.x = f2bf(v.x); r.y = f2bf(v.y); r.z = f2bf(v.z); r.w = f2bf(v.w);
    *(ushort4*)dst = r;
  }
}

// ---------------- bucketed CSR build (no scan) ----------------
// fill1: independent return-atomics + coalesced pos write (round-4 proven pattern)
__global__ void fill1_kernel(const int* __restrict__ dst, int* __restrict__ cnt,
                             int* __restrict__ pos, int E){
  int e = (blockIdx.x * 256 + threadIdx.x) * 4;
  if (e + 4 <= E){
    int4 d = *(const int4*)(dst + e);
    int4 p;
    p.x = atomicAdd(&cnt[d.x], 1);
    p.y = atomicAdd(&cnt[d.y], 1);
    p.z = atomicAdd(&cnt[d.z], 1);
    p.w = atomicAdd(&cnt[d.w], 1);
    *(int4*)(pos + e) = p;
  } else {
    for (; e < E; ++e) pos[e] = atomicAdd(&cnt[dst[e]], 1);
  }
}

// fill2: atomic-free scatter into fixed-capacity per-node buckets
__global__ void fill2_kernel(const int* __restrict__ src, const int* __restrict__ dst,
                             const int* __restrict__ pos, int* __restrict__ slots, int E){
  int e = (blockIdx.x * 256 + threadIdx.x) * 4;
  if (e + 4 <= E){
    int4 d = *(const int4*)(dst + e);
    int4 p = *(const int4*)(pos + e);
    int4 s = *(const int4*)(src + e);
    slots[d.x * MAXDEG + p.x] = s.x;
    slots[d.y * MAXDEG + p.y] = s.y;
    slots[d.z * MAXDEG + p.z] = s.z;
    slots[d.w * MAXDEG + p.w] = s.w;
  } else {
    for (; e < E; ++e) slots[dst[e] * MAXDEG + pos[e]] = src[e];
  }
}

// ---------------- BN param computation (device helper, threads<128) ----------------
// stats stored as 8 sub-accumulators of 256 floats each (sum | sumsq)
__device__ inline void bn_params8(const float* __restrict__ st, const float* __restrict__ gA,
                                  const float* __restrict__ gB, const float* __restrict__ bB,
                                  int mode, float* sS, float* sT){
  int c = threadIdx.x;
  if (c < 128){
    float s0 = 0.f, s1 = 0.f;
#pragma unroll
    for (int k = 0; k < 8; ++k){
      s0 += st[k * 256 + c];
      s1 += st[k * 256 + 128 + c];
    }
    const float invN = 1.f / (float)NN;
    float mu = s0 * invN;
    float var = fmaxf(s1 * invN - mu * mu, 0.f);
    float S, T;
    if (mode == 0){
      S = gA[c] * rsqrtf(var + BN_EPS);
      T = gB[c] - mu * S;
    } else {
      float inv2 = rsqrtf(var + BN_EPS);
      float tt = gA[c] * inv2;
      float inv3 = rsqrtf(tt * tt * var + BN_EPS);
      S = tt * inv3 * gB[c];
      T = bB[c] - mu * S;
    }
    sS[c] = S; sT[c] = T;
  }
}

// ---------------- fused aggregation + fc1 GEMM ----------------
// Phase 1: each wave aggregates its 16 output rows (4 nodes at a time, 16 lanes/row,
//          optional composed bn3(bn2(.))+relu on each gathered row) into a wave-
//          private LDS A-tile.
// Phase 2: Y = A @ W^T + bias, stats accumulated.
// NOTE (R6-R12 post-mortems): this (512,4)/8-wave/391-block configuration is the
// measured saddle point — gather live-set needs ~64-72 VGPR; more residency
// (512,6: VGPR 40) or more ILP (dual-node, hoist) both spill; fewer bounds
// (512,2) halves occupancy. Six variants bracketed it; all regressed.
template<bool AFF>
__global__ __launch_bounds__(512, 4) void aggemm_t(const ushort* __restrict__ xin,
                                                   const int* __restrict__ deg,
                                                   const int* __restrict__ slots,
                                                   const ushort* __restrict__ W,
                                                   const float* __restrict__ bias,
                                                   ushort* __restrict__ Yb,
                                                   float* __restrict__ statsOut,
                                                   const float* __restrict__ statsIn,
                                                   const float* __restrict__ g2,
                                                   const float* __restrict__ g3,
                                                   const float* __restrict__ b3){
  __shared__ uint4v w4[128 * 17];
  __shared__ uint4v a4[8][16 * 17];   // per-wave 16x128 bf16 A-tile (+pad)
  __shared__ float ssum[128];
  __shared__ float ssq[128];
  __shared__ float sS[128];
  __shared__ float sT[128];

  const uint4v* Wg = (const uint4v*)W;
  for (int c = threadIdx.x; c < 2048; c += 512){
    w4[(c >> 4) * 17 + (c & 15)] = Wg[c];
  }
  if (AFF) bn_params8(statsIn, g2, g3, b3, 1, sS, sT);
  if (threadIdx.x < 128){ ssum[threadIdx.x] = 0.f; ssq[threadIdx.x] = 0.f; }
  __syncthreads();

  int wave = threadIdx.x >> 6;
  int lane = threadIdx.x & 63;
  int grp  = lane >> 4;          // which of the 4 concurrent node slots
  int col  = lane & 15;          // 16B chunk within the 256B row
  int tile = blockIdx.x * 8 + wave;
  bool tv = tile < NTILES;

  float S[8], T[8];
  if (AFF){
#pragma unroll
    for (int k = 0; k < 8; ++k){ S[k] = sS[col * 8 + k]; T[k] = sT[col * 8 + k]; }
  }

  const uint4v* x4 = (const uint4v*)xin;

#define INIT8(v)                                                                \
  if (AFF){                                                                     \
    a[0]=fmaxf(bflo((v).x)*S[0]+T[0],0.f); a[1]=fmaxf(bfhi((v).x)*S[1]+T[1],0.f); \
    a[2]=fmaxf(bflo((v).y)*S[2]+T[2],0.f); a[3]=fmaxf(bfhi((v).y)*S[3]+T[3],0.f); \
    a[4]=fmaxf(bflo((v).z)*S[4]+T[4],0.f); a[5]=fmaxf(bfhi((v).z)*S[5]+T[5],0.f); \
    a[6]=fmaxf(bflo((v).w)*S[6]+T[6],0.f); a[7]=fmaxf(bfhi((v).w)*S[7]+T[7],0.f); \
  } else {                                                                      \
    a[0]=bflo((v).x); a[1]=bfhi((v).x); a[2]=bflo((v).y); a[3]=bfhi((v).y);     \
    a[4]=bflo((v).z); a[5]=bfhi((v).z); a[6]=bflo((v).w); a[7]=bfhi((v).w);     \
  }

#define ACC8(v)                                                                 \
  if (AFF){                                                                     \
    a[0]+=fmaxf(bflo((v).x)*S[0]+T[0],0.f); a[1]+=fmaxf(bfhi((v).x)*S[1]+T[1],0.f); \
    a[2]+=fmaxf(bflo((v).y)*S[2]+T[2],0.f); a[3]+=fmaxf(bfhi((v).y)*S[3]+T[3],0.f); \
    a[4]+=fmaxf(bflo((v).z)*S[4]+T[4],0.f); a[5]+=fmaxf(bfhi((v).z)*S[5]+T[5],0.f); \
    a[6]+=fmaxf(bflo((v).w)*S[6]+T[6],0.f); a[7]+=fmaxf(bfhi((v).w)*S[7]+T[7],0.f); \
  } else {                                                                      \
    a[0]+=bflo((v).x); a[1]+=bfhi((v).x); a[2]+=bflo((v).y); a[3]+=bfhi((v).y); \
    a[4]+=bflo((v).z); a[5]+=bfhi((v).z); a[6]+=bflo((v).w); a[7]+=bfhi((v).w); \
  }

  if (tv){
    for (int it = 0; it < 4; ++it){
      int node = tile * 16 + it * 4 + grp;
      int e = deg[node];
      const int* sl = slots + node * MAXDEG;
      float a[8];
      {
        uint4v v = x4[node * 16 + col];
        INIT8(v);
      }
      int j = 0;
      for (; j + 8 <= e; j += 8){
        int i0 = sl[j+0], i1 = sl[j+1], i2 = sl[j+2], i3 = sl[j+3];
        int i4 = sl[j+4], i5 = sl[j+5], i6 = sl[j+6], i7 = sl[j+7];
        uint4v v0 = x4[i0 * 16 + col];
        uint4v v1 = x4[i1 * 16 + col];
        uint4v v2 = x4[i2 * 16 + col];
        uint4v v3 = x4[i3 * 16 + col];
        uint4v v4 = x4[i4 * 16 + col];
        uint4v v5 = x4[i5 * 16 + col];
        uint4v v6 = x4[i6 * 16 + col];
        uint4v v7 = x4[i7 * 16 + col];
        ACC8(v0); ACC8(v1); ACC8(v2); ACC8(v3);
        ACC8(v4); ACC8(v5); ACC8(v6); ACC8(v7);
      }
      for (; j + 4 <= e; j += 4){
        int i0 = sl[j+0], i1 = sl[j+1], i2 = sl[j+2], i3 = sl[j+3];
        uint4v v0 = x4[i0 * 16 + col];
        uint4v v1 = x4[i1 * 16 + col];
        uint4v v2 = x4[i2 * 16 + col];
        uint4v v3 = x4[i3 * 16 + col];
        ACC8(v0); ACC8(v1); ACC8(v2); ACC8(v3);
      }
      for (; j < e; ++j){
        uint4v v = x4[sl[j] * 16 + col];
        ACC8(v);
      }
      uint4v o;
      o.x = pk2(a[0], a[1]); o.y = pk2(a[2], a[3]);
      o.z = pk2(a[4], a[5]); o.w = pk2(a[6], a[7]);
      a4[wave][(it * 4 + grp) * 17 + col] = o;
    }
  }
#undef INIT8
#undef ACC8
  __syncthreads();

  // ---- phase 2: MFMA from the wave-private LDS A-tile ----
  int m = lane & 15, q = lane >> 4;
  f32x4 acc[8];
#pragma unroll
  for (int i = 0; i < 8; ++i) acc[i] = (f32x4)0.f;

#pragma unroll
  for (int kt = 0; kt < 4; ++kt){
    uint4v t = a4[wave][m * 17 + kt * 4 + q];
    short8 af = *(short8*)&t;
#pragma unroll
    for (int to = 0; to < 8; ++to){
      uint4v bw = w4[(to * 16 + m) * 17 + kt * 4 + q];
      acc[to] = __builtin_amdgcn_mfma_f32_16x16x32_bf16(af, *(short8*)&bw, acc[to], 0, 0, 0);
    }
  }

#pragma unroll
  for (int to = 0; to < 8; ++to){
    int colo = to * 16 + m;
    float bc = bias[colo];
    float ls = 0.f, lq = 0.f;
    if (tv){
#pragma unroll
      for (int r = 0; r < 4; ++r){
        float v = acc[to][r] + bc;
        int row = tile * 16 + q * 4 + r;
        __builtin_nontemporal_store(__builtin_bit_cast(ushort, f2bf(v)), Yb + row * 128 + colo);
        ls += v; lq += v * v;
      }
    }
    ls += __shfl_xor(ls, 16); lq += __shfl_xor(lq, 16);
    ls += __shfl_xor(ls, 32); lq += __shfl_xor(lq, 32);
    if (tv && q == 0){ atomicAdd(&ssum[colo], ls); atomicAdd(&ssq[colo], lq); }
  }
  __syncthreads();
  if (threadIdx.x < 128){
    int sb = (blockIdx.x & 7) * 256;
    atomicAdd(&statsOut[sb + threadIdx.x], ssum[threadIdx.x]);
    atomicAdd(&statsOut[sb + 128 + threadIdx.x], ssq[threadIdx.x]);
  }
}

// ---------------- unified GEMM: Y = [relu(affine(A))] @ W^T + bias ----------------
// 512 threads, 8 waves, 1 tile (16 rows) per wave; grid 391.
__global__ __launch_bounds__(512) void gemm_kernel(const ushort* __restrict__ A,
                                                   const ushort* __restrict__ W,
                                                   const float* __restrict__ bias,
                                                   ushort* __restrict__ Yb,
                                                   float* __restrict__ Yf,
                                                   float* __restrict__ statsOut,
                                                   const float* __restrict__ statsIn,
                                                   const float* __restrict__ gA,
                                                   const float* __restrict__ gB,
                                                   const float* __restrict__ bB,
                                                   int mode){
  __shared__ uint4v w4[128 * 17];
  __shared__ float ssum[128];
  __shared__ float ssq[128];
  __shared__ float sS[128];
  __shared__ float sT[128];
  const uint4v* Wg = (const uint4v*)W;
  for (int c = threadIdx.x; c < 2048; c += 512){
    w4[(c >> 4) * 17 + (c & 15)] = Wg[c];
  }
  if (statsIn) bn_params8(statsIn, gA, gB, bB, mode, sS, sT);
  if (threadIdx.x < 128){ ssum[threadIdx.x] = 0.f; ssq[threadIdx.x] = 0.f; }
  __syncthreads();

  int wave = threadIdx.x >> 6;
  int lane = threadIdx.x & 63;
  int m = lane & 15, q = lane >> 4;
  int tile = blockIdx.x * 8 + wave;
  bool tv = tile < NTILES;
  const uint4v* A4 = (const uint4v*)A;

  f32x4 acc[8];
#pragma unroll
  for (int i = 0; i < 8; ++i) acc[i] = (f32x4)0.f;

#pragma unroll
  for (int kt = 0; kt < 4; ++kt){
    short8 af = (short8)0;
    if (tv){
      uint4v t = __builtin_nontemporal_load(A4 + (tile * 16 + m) * 16 + kt * 4 + q);
      if (statsIn){
        int kc = kt * 32 + q * 8;
        uint4v pk;
        pk.x = pk2(fmaxf(bflo(t.x)*sS[kc+0]+sT[kc+0],0.f),
                   fmaxf(bfhi(t.x)*sS[kc+1]+sT[kc+1],0.f));
        pk.y = pk2(fmaxf(bflo(t.y)*sS[kc+2]+sT[kc+2],0.f),
                   fmaxf(bfhi(t.y)*sS[kc+3]+sT[kc+3],0.f));
        pk.z = pk2(fmaxf(bflo(t.z)*sS[kc+4]+sT[kc+4],0.f),
                   fmaxf(bfhi(t.z)*sS[kc+5]+sT[kc+5],0.f));
        pk.w = pk2(fmaxf(bflo(t.w)*sS[kc+6]+sT[kc+6],0.f),
                   fmaxf(bfhi(t.w)*sS[kc+7]+sT[kc+7],0.f));
        t = pk;
      }
      af = *(short8*)&t;
    }
#pragma unroll
    for (int to = 0; to < 8; ++to){
      uint4v bw = w4[(to * 16 + m) * 17 + kt * 4 + q];
      acc[to] = __builtin_amdgcn_mfma_f32_16x16x32_bf16(af, *(short8*)&bw, acc[to], 0, 0, 0);
    }
  }

  bool dost = (statsOut != nullptr);
#pragma unroll
  for (int to = 0; to < 8; ++to){
    int col = to * 16 + m;
    float bc = bias[col];
    float ls = 0.f, lq = 0.f;
    if (tv){
#pragma unroll
      for (int r = 0; r < 4; ++r){
        float v = acc[to][r] + bc;
        int row = tile * 16 + q * 4 + r;
        if (Yb) __builtin_nontemporal_store(__builtin_bit_cast(ushort, f2bf(v)), Yb + row * 128 + col);
        else    __builtin_nontemporal_store(v, Yf + row * 128 + col);
        ls += v; lq += v * v;
      }
    }
    if (dost){
      ls += __shfl_xor(ls, 16); lq += __shfl_xor(lq, 16);
      ls += __shfl_xor(ls, 32); lq += __shfl_xor(lq, 32);
      if (tv && q == 0){ atomicAdd(&ssum[col], ls); atomicAdd(&ssq[col], lq); }
    }
  }
  if (dost){
    __syncthreads();
    if (threadIdx.x < 128){
      int sb = (blockIdx.x & 7) * 256;
      atomicAdd(&statsOut[sb + threadIdx.x], ssum[threadIdx.x]);
      atomicAdd(&statsOut[sb + 128 + threadIdx.x], ssq[threadIdx.x]);
    }
  }
}

extern "C" void kernel_launch(void* const* d_in, const int* in_sizes, int n_in,
                              void* d_out, int out_size, void* d_ws, size_t ws_size,
                              hipStream_t stream) {
  const float* x     = (const float*)d_in[0];
  const int*   ei    = (const int*)d_in[1];
  const float* fc1_w = (const float*)d_in[2];
  const float* fc1_b = (const float*)d_in[3];
  const float* bn1_g = (const float*)d_in[4];
  const float* bn1_b = (const float*)d_in[5];
  const float* fc2_w = (const float*)d_in[6];
  const float* fc2_b = (const float*)d_in[7];
  const float* bn2_g = (const float*)d_in[8];
  const float* bn3_g = (const float*)d_in[10];
  const float* bn3_b = (const float*)d_in[11];
  const float* fc_w  = (const float*)d_in[12];
  const float* fc_b  = (const float*)d_in[13];

  int E = in_sizes[1] / 2;
  const int* srcp = ei;
  const int* dstp = ei + E;

  char* ws = (char*)d_ws;
  int*    cnt    = (int*)(ws + 0);           // N ints (degree)
  float*  stats  = (float*)(ws + 200064);    // 8 slices x 8 sub x 256 floats = 64KB
  int*    pos    = (int*)(ws + 265600);      // E ints
  int*    slots  = (int*)(ws + 3465600);     // N*MAXDEG ints = 12.8 MB
  ushort* wb     = (ushort*)(ws + 16265600); // 147456 bf16
  ushort* xb     = (ushort*)(ws + 16560512); // N*128 bf16
  ushort* y1b    = (ushort*)(ws + 29360512); // N*128 bf16
  ushort* y2b    = (ushort*)(ws + 42160512); // N*128 bf16

  // cnt + stats are contiguous: one memset
  hipMemsetAsync(ws, 0, 265600, stream);

  cast_all<<<2048, 256, 0, stream>>>(x, fc1_w, fc2_w, fc_w, xb, wb);

  const int EB4 = (E / 4 + 255) / 256 + 1;
  fill1_kernel<<<EB4, 256, 0, stream>>>(dstp, cnt, pos, E);
  fill2_kernel<<<EB4, 256, 0, stream>>>(srcp, dstp, pos, slots, E);

  const int gb = (NTILES + 7) / 8;  // 391 blocks x 8 waves

  for (int i = 0; i < NL; ++i){
    // fused agg + fc1: gather (+bn23 affine for i>0) -> LDS tile -> MFMA -> y1b, stats1
    if (i == 0){
      aggemm_t<false><<<gb, 512, 0, stream>>>(xb, cnt, slots, wb + i * 16384,
                                              fc1_b + i * 128, y1b,
                                              stats + (i * 2) * 2048,
                                              nullptr, nullptr, nullptr, nullptr);
    } else {
      aggemm_t<true><<<gb, 512, 0, stream>>>(y2b, cnt, slots, wb + i * 16384,
                                             fc1_b + i * 128, y1b,
                                             stats + (i * 2) * 2048,
                                             stats + ((i - 1) * 2 + 1) * 2048,
                                             bn2_g + (i - 1) * 128,
                                             bn3_g + (i - 1) * 128,
                                             bn3_b + (i - 1) * 128);
    }
    // fc2: relu(bn1(y1b)) -> y2b (bf16), stats2; bn1 params inline from stats1
    gemm_kernel<<<gb, 512, 0, stream>>>(y1b, wb + 65536 + i * 16384, fc2_b + i * 128,
                                        y2b, nullptr, stats + (i * 2 + 1) * 2048,
                                        stats + (i * 2) * 2048, bn1_g + i * 128,
                                        bn1_b + i * 128, nullptr, 0);
  }

  // classifier: relu(bn3(bn2(y2b)))@fc_w^T + fc_b -> f32 out; bn23 params inline
  gemm_kernel<<<gb, 512, 0, stream>>>(y2b, wb + 131072, fc_b,
                                      nullptr, (float*)d_out, nullptr,
                                      stats + 7 * 2048, bn2_g + 384,
                                      bn3_g + 384, bn3_b + 384, 1);
}